// Round 1
// 566.964 us; speedup vs baseline: 1.0357x; 1.0357x over previous
//
#include <hip/hip_runtime.h>

#define GAS __attribute__((address_space(1)))
#define LAS __attribute__((address_space(3)))

typedef __attribute__((ext_vector_type(8))) _Float16 half8;
typedef __attribute__((ext_vector_type(4))) float floatx4;
typedef __attribute__((ext_vector_type(4))) unsigned short ushort4v;

static constexpr int B_  = 16;
static constexpr int LQ  = 512;
static constexpr int LC  = 2048;
static constexpr int D_  = 1024;
static constexpr int DO  = 2048;   // output feature dim (concat)
static constexpr int MT  = 64;     // context rows per block
static constexpr int BUFSZ = 36864; // 32 KiB Q-frag blocks + 4 KiB C-frag blocks

__device__ __forceinline__ void gl2lds16(const void* g, void* l) {
  __builtin_amdgcn_global_load_lds((const GAS unsigned int*)g,
                                   (LAS unsigned int*)l, 16, 0, 0);
}

__device__ __forceinline__ unsigned short f2h(float f) {
  return __builtin_bit_cast(unsigned short, (_Float16)f);   // v_cvt_f16_f32 RNE
}

// ---- Q prep: fp32 -> fp16 qh[b][q][d] AND transposed qth[b][d][q] ----
__global__ void qprep_kernel(const float* __restrict__ q,
                             unsigned short* __restrict__ qh,
                             unsigned short* __restrict__ qt) {
  __shared__ unsigned short t[32][33];
  const int b = blockIdx.z, d0 = blockIdx.x * 32, q0 = blockIdx.y * 32;
  const float* src = q + (size_t)b * LQ * D_;
  unsigned short* dq = qh + (size_t)b * LQ * D_;
  unsigned short* dt = qt + (size_t)b * D_ * LQ;
  for (int i = threadIdx.y; i < 32; i += 8) {
    const unsigned short h = f2h(src[(size_t)(q0 + i) * D_ + d0 + threadIdx.x]);
    dq[(size_t)(q0 + i) * D_ + d0 + threadIdx.x] = h;
    t[i][threadIdx.x] = h;
  }
  __syncthreads();
  for (int i = threadIdx.y; i < 32; i += 8)
    dt[(size_t)(d0 + i) * LQ + q0 + threadIdx.x] = t[threadIdx.x][i];
}

// ---- C prep: fp32 -> fp16 ch, PLUS passthrough out[:, :D] = context ----
__global__ void cprep_kernel(const float* __restrict__ src,
                             unsigned short* __restrict__ dst,
                             float* __restrict__ out) {
  const int nrows = B_ * LC;
  for (int row = blockIdx.x; row < nrows; row += gridDim.x) {
    const float4 v = ((const float4*)(src + (size_t)row * D_))[threadIdx.x];
    ushort4v h;
    h.x = f2h(v.x); h.y = f2h(v.y); h.z = f2h(v.z); h.w = f2h(v.w);
    ((ushort4v*)(dst + (size_t)row * D_))[threadIdx.x] = h;
    ((float4*)(out + (size_t)row * DO))[threadIdx.x] = v;
  }
}

__launch_bounds__(512, 4)
__global__ void attn_main(const unsigned short* __restrict__ qg,   // Qh fp16
                          const unsigned short* __restrict__ cg,   // Ch fp16
                          const unsigned short* __restrict__ qtg,  // QTh fp16
                          unsigned short* __restrict__ pg,         // P fp16 ws
                          float* __restrict__ og) {                // out fp32
  // LDS: 2 x (32 KiB Q-frags + 4 KiB C-frags) double buffer + softmax scratch
  __shared__ __align__(16) char smem[2 * BUFSZ + 2048 + 256];
  float* redf    = (float*)(smem + 2 * BUFSZ);          // [8 waves][64 rows]
  float* rowstat = (float*)(smem + 2 * BUFSZ + 2048);   // [64] rowmax / rowinv

  const int tid  = threadIdx.x;
  const int wave = tid >> 6;
  const int lane = tid & 63;
  const int l15  = lane & 15;
  const int quad = lane >> 4;
  const int q8   = quad * 8;

  const int b    = blockIdx.x & 15;   // XCD-swizzle: batch b -> XCD b%8
  const int tile = blockIdx.x >> 4;
  const int c0   = tile * MT;

  const unsigned short* Q  = qg  + (size_t)b * LQ * D_;
  const unsigned short* C  = cg  + (size_t)b * LC * D_;
  const unsigned short* QT = qtg + (size_t)b * D_ * LQ;
  unsigned short*       P  = pg  + (size_t)b * LC * LQ;
  float*                O  = og  + (size_t)b * LC * DO;

  floatx4 acc[4][4];

  // waves 0-3 issue 5 gl2lds per step, waves 4-7 issue 4
  auto stage1 = [&](int it, char* buf) {
    const int k0 = it * 32;
#pragma unroll
    for (int j = 0; j < 5; ++j) {
      const int bb = wave + j * 8;
      if (bb < 32) {          // Q frag block (B operand): rows = q index
        gl2lds16(Q + (size_t)(bb * 16 + l15) * D_ + k0 + q8, buf + bb * 1024);
      } else if (bb < 36) {   // C frag block (A operand): rows = context rows
        const int mt = bb - 32;
        gl2lds16(C + (size_t)(c0 + mt * 16 + l15) * D_ + k0 + q8,
                 buf + 32768 + mt * 1024);
      }
    }
  };

  auto stage2 = [&](int nh, int itq, char* buf) {
    const int kq = itq * 32;
#pragma unroll
    for (int j = 0; j < 5; ++j) {
      const int bb = wave + j * 8;
      if (bb < 32) {          // QT frag block: rows = d index
        gl2lds16(QT + (size_t)(nh * 512 + bb * 16 + l15) * LQ + kq + q8,
                 buf + bb * 1024);
      } else if (bb < 36) {   // P frag block: rows = context rows
        const int mt = bb - 32;
        gl2lds16(P + (size_t)(c0 + mt * 16 + l15) * LQ + kq + q8,
                 buf + 32768 + mt * 1024);
      }
    }
  };

  auto compute = [&](const char* buf) {
    half8 af[4], bf[4];
#pragma unroll
    for (int mt = 0; mt < 4; ++mt)
      af[mt] = *(const half8*)(buf + 32768 + mt * 1024 + lane * 16);
#pragma unroll
    for (int nt = 0; nt < 4; ++nt)
      bf[nt] = *(const half8*)(buf + (wave * 4 + nt) * 1024 + lane * 16);
#pragma unroll
    for (int mt = 0; mt < 4; ++mt)
#pragma unroll
      for (int nt = 0; nt < 4; ++nt)
        acc[mt][nt] = __builtin_amdgcn_mfma_f32_16x16x32_f16(
            af[mt], bf[nt], acc[mt][nt], 0, 0, 0);
  };

  // counted wait: leave the just-issued (next-tile) stage loads in flight,
  // require the previous tile's loads to have landed in LDS
  auto wait_prev = [&]() {
    if (wave < 4) asm volatile("s_waitcnt vmcnt(5)" ::: "memory");
    else          asm volatile("s_waitcnt vmcnt(4)" ::: "memory");
  };

#pragma unroll
  for (int i = 0; i < 4; ++i)
#pragma unroll
    for (int j = 0; j < 4; ++j) acc[i][j] = floatx4{0.f, 0.f, 0.f, 0.f};

  // ========= Phase 1: S = C_tile (64xK) * Q^T (Kx512), double-buffered ====
  stage1(0, smem);
  int cur = 0;
#pragma unroll 1
  for (int it = 0; it < 32; ++it) {
    if (it + 1 < 32) {
      stage1(it + 1, smem + (cur ^ 1) * BUFSZ);   // issue next tile first
      wait_prev();                                // current tile resident
    } else {
      asm volatile("s_waitcnt vmcnt(0)" ::: "memory");
    }
    __builtin_amdgcn_s_barrier();                 // all waves: buf[cur] staged
    __builtin_amdgcn_sched_barrier(0);
    compute(smem + cur * BUFSZ);                  // ds_reads complete pre-MFMA
    asm volatile("" ::: "memory");
    __builtin_amdgcn_s_barrier();                 // buf[cur] free to overwrite
    cur ^= 1;
  }

  // ================= softmax over n (=Lq) per context row ================
  // C/D layout: col = l15, row = quad*4 + reg  [m89/m91]
#pragma unroll
  for (int mt = 0; mt < 4; ++mt)
#pragma unroll
    for (int r = 0; r < 4; ++r) {
      float m = fmaxf(fmaxf(acc[mt][0][r], acc[mt][1][r]),
                      fmaxf(acc[mt][2][r], acc[mt][3][r]));
      m = fmaxf(m, __shfl_xor(m, 1, 64));
      m = fmaxf(m, __shfl_xor(m, 2, 64));
      m = fmaxf(m, __shfl_xor(m, 4, 64));
      m = fmaxf(m, __shfl_xor(m, 8, 64));
      if (l15 == 0) redf[wave * 64 + mt * 16 + quad * 4 + r] = m;
    }
  __syncthreads();
  if (tid < 64) {
    float m = redf[tid];
#pragma unroll
    for (int w = 1; w < 8; ++w) m = fmaxf(m, redf[w * 64 + tid]);
    rowstat[tid] = m;
  }
  __syncthreads();
#pragma unroll
  for (int mt = 0; mt < 4; ++mt)
#pragma unroll
    for (int r = 0; r < 4; ++r) {
      const float m = rowstat[mt * 16 + quad * 4 + r];
      float s = 0.f;
#pragma unroll
      for (int nt = 0; nt < 4; ++nt) {
        const float e = __expf(acc[mt][nt][r] - m);
        acc[mt][nt][r] = e;
        s += e;
      }
      s += __shfl_xor(s, 1, 64);
      s += __shfl_xor(s, 2, 64);
      s += __shfl_xor(s, 4, 64);
      s += __shfl_xor(s, 8, 64);
      if (l15 == 0) redf[wave * 64 + mt * 16 + quad * 4 + r] = s;
    }
  __syncthreads();
  if (tid < 64) {
    float s = 0.f;
#pragma unroll
    for (int w = 0; w < 8; ++w) s += redf[w * 64 + tid];
    rowstat[tid] = 1.0f / s;
  }
  __syncthreads();
  // write P (fp16) to workspace — L2-resident, read back by this block only
#pragma unroll
  for (int mt = 0; mt < 4; ++mt)
#pragma unroll
    for (int r = 0; r < 4; ++r) {
      const float inv = rowstat[mt * 16 + quad * 4 + r];
      const size_t rowoff =
          (size_t)(c0 + mt * 16 + quad * 4 + r) * LQ + wave * 64 + l15;
#pragma unroll
      for (int nt = 0; nt < 4; ++nt)
        P[rowoff + nt * 16] = f2h(acc[mt][nt][r] * inv);
    }
  asm volatile("s_waitcnt vmcnt(0)" ::: "memory");  // drain P stores
  __syncthreads();                                  // all waves' P visible

  // ========= Phase 2: O = P (64x512) * Q (512x1024), double-buffered ======
#pragma unroll 1
  for (int nh = 0; nh < 2; ++nh) {
#pragma unroll
    for (int i = 0; i < 4; ++i)
#pragma unroll
      for (int j = 0; j < 4; ++j) acc[i][j] = floatx4{0.f, 0.f, 0.f, 0.f};
    stage2(nh, 0, smem);
    cur = 0;
#pragma unroll 1
    for (int itq = 0; itq < 16; ++itq) {
      if (itq + 1 < 16) {
        stage2(nh, itq + 1, smem + (cur ^ 1) * BUFSZ);
        wait_prev();
      } else {
        asm volatile("s_waitcnt vmcnt(0)" ::: "memory");
      }
      __builtin_amdgcn_s_barrier();
      __builtin_amdgcn_sched_barrier(0);
      compute(smem + cur * BUFSZ);
      asm volatile("" ::: "memory");
      __builtin_amdgcn_s_barrier();
      cur ^= 1;
    }
    // epilogue: out[:, D + nh*512 + col] = O chunk (fp32)
#pragma unroll
    for (int mt = 0; mt < 4; ++mt)
#pragma unroll
      for (int r = 0; r < 4; ++r) {
        const size_t rowoff = (size_t)(c0 + mt * 16 + quad * 4 + r) * DO +
                              D_ + nh * 512 + wave * 64 + l15;
#pragma unroll
        for (int nt = 0; nt < 4; ++nt)
          O[rowoff + nt * 16] = acc[mt][nt][r];
      }
  }
}

extern "C" void kernel_launch(void* const* d_in, const int* in_sizes, int n_in,
                              void* d_out, int out_size, void* d_ws, size_t ws_size,
                              hipStream_t stream) {
  (void)in_sizes; (void)n_in; (void)out_size; (void)ws_size;
  const float* q = (const float*)d_in[0];
  const float* c = (const float*)d_in[1];
  float* out = (float*)d_out;
  // workspace layout (fp16 halves): Qh 16MiB | Ch 64MiB | QTh 16MiB | P 32MiB
  unsigned short* qh  = (unsigned short*)d_ws;
  unsigned short* ch  = qh  + (size_t)B_ * LQ * D_;
  unsigned short* qth = ch  + (size_t)B_ * LC * D_;
  unsigned short* p   = qth + (size_t)B_ * D_ * LQ;
  qprep_kernel<<<dim3(D_ / 32, LQ / 32, B_), dim3(32, 8), 0, stream>>>(q, qh, qth);
  cprep_kernel<<<2048, 256, 0, stream>>>(c, ch, out);
  attn_main<<<dim3(B_ * (LC / MT)), dim3(512), 0, stream>>>(qh, ch, qth, p, out);
}

// Round 3
// 565.807 us; speedup vs baseline: 1.0379x; 1.0020x over previous
//
#include <hip/hip_runtime.h>

#define GAS __attribute__((address_space(1)))
#define LAS __attribute__((address_space(3)))

typedef __attribute__((ext_vector_type(8))) _Float16 half8;
typedef __attribute__((ext_vector_type(4))) float floatx4;
typedef __attribute__((ext_vector_type(4))) unsigned short ushort4v;

static constexpr int B_  = 16;
static constexpr int LQ  = 512;
static constexpr int LC  = 2048;
static constexpr int D_  = 1024;
static constexpr int DO  = 2048;   // output feature dim (concat)
static constexpr int MT  = 64;     // context rows per block
static constexpr int BUFSZ = 36864; // 32 KiB Q-frag blocks + 4 KiB C-frag blocks

__device__ __forceinline__ void gl2lds16(const void* g, void* l) {
  __builtin_amdgcn_global_load_lds((const GAS unsigned int*)g,
                                   (LAS unsigned int*)l, 16, 0, 0);
}

__device__ __forceinline__ unsigned short f2h(float f) {
  return __builtin_bit_cast(unsigned short, (_Float16)f);   // v_cvt_f16_f32 RNE
}

// counted vmcnt: waves 0-3 carry 5 loads/iter, waves 4-7 carry 4
#define WAITV(a, b)                                                        \
  do {                                                                     \
    if (wave < 4) asm volatile("s_waitcnt vmcnt(" #a ")" ::: "memory");    \
    else          asm volatile("s_waitcnt vmcnt(" #b ")" ::: "memory");    \
  } while (0)

// ---- Q prep: fp32 -> fp16 qh[b][q][d] AND transposed qth[b][d][q] ----
__global__ void qprep_kernel(const float* __restrict__ q,
                             unsigned short* __restrict__ qh,
                             unsigned short* __restrict__ qt) {
  __shared__ unsigned short t[32][33];
  const int b = blockIdx.z, d0 = blockIdx.x * 32, q0 = blockIdx.y * 32;
  const float* src = q + (size_t)b * LQ * D_;
  unsigned short* dq = qh + (size_t)b * LQ * D_;
  unsigned short* dt = qt + (size_t)b * D_ * LQ;
  for (int i = threadIdx.y; i < 32; i += 8) {
    const unsigned short h = f2h(src[(size_t)(q0 + i) * D_ + d0 + threadIdx.x]);
    dq[(size_t)(q0 + i) * D_ + d0 + threadIdx.x] = h;
    t[i][threadIdx.x] = h;
  }
  __syncthreads();
  for (int i = threadIdx.y; i < 32; i += 8)
    dt[(size_t)(d0 + i) * LQ + q0 + threadIdx.x] = t[threadIdx.x][i];
}

// ---- C prep: fp32 -> fp16 ch, PLUS passthrough out[:, :D] = context ----
__global__ void cprep_kernel(const float* __restrict__ src,
                             unsigned short* __restrict__ dst,
                             float* __restrict__ out) {
  const int nrows = B_ * LC;
  for (int row = blockIdx.x; row < nrows; row += gridDim.x) {
    const float4 v = ((const float4*)(src + (size_t)row * D_))[threadIdx.x];
    ushort4v h;
    h.x = f2h(v.x); h.y = f2h(v.y); h.z = f2h(v.z); h.w = f2h(v.w);
    ((ushort4v*)(dst + (size_t)row * D_))[threadIdx.x] = h;
    ((float4*)(out + (size_t)row * DO))[threadIdx.x] = v;
  }
}

__launch_bounds__(512, 1)
__global__ void attn_main(const unsigned short* __restrict__ qg,   // Qh fp16
                          const unsigned short* __restrict__ cg,   // Ch fp16
                          const unsigned short* __restrict__ qtg,  // QTh fp16
                          unsigned short* __restrict__ pg,         // P fp16 ws
                          float* __restrict__ og) {                // out fp32
  // LDS: 4 x 36 KiB ring (depth-3 prefetch) + softmax reduction scratch
  __shared__ __align__(16) char smem[4 * BUFSZ + 2048 + 256];
  float* redf    = (float*)(smem + 4 * BUFSZ);          // [8 waves][64 rows]
  float* rowstat = (float*)(smem + 4 * BUFSZ + 2048);   // [64] rowmax / rowinv

  const int tid  = threadIdx.x;
  const int wave = tid >> 6;
  const int lane = tid & 63;
  const int l15  = lane & 15;
  const int quad = lane >> 4;
  const int q8   = quad * 8;

  const int b    = blockIdx.x & 15;   // XCD-swizzle: batch b -> XCD b%8
  const int tile = blockIdx.x >> 4;
  const int c0   = tile * MT;

  const unsigned short* Q  = qg  + (size_t)b * LQ * D_;
  const unsigned short* C  = cg  + (size_t)b * LC * D_;
  const unsigned short* QT = qtg + (size_t)b * D_ * LQ;
  unsigned short*       P  = pg  + (size_t)b * LC * LQ;
  float*                O  = og  + (size_t)b * LC * DO;

  floatx4 acc[4][4];

  // waves 0-3 issue 5 gl2lds per tile, waves 4-7 issue 4
  auto stage1 = [&](int it, char* buf) {
    const int k0 = it * 32;
#pragma unroll
    for (int j = 0; j < 5; ++j) {
      const int bb = wave + j * 8;
      if (bb < 32) {          // Q frag block (B operand): rows = q index
        gl2lds16(Q + (size_t)(bb * 16 + l15) * D_ + k0 + q8, buf + bb * 1024);
      } else if (bb < 36) {   // C frag block (A operand): rows = context rows
        const int mt = bb - 32;
        gl2lds16(C + (size_t)(c0 + mt * 16 + l15) * D_ + k0 + q8,
                 buf + 32768 + mt * 1024);
      }
    }
  };

  auto stage2 = [&](int u, char* buf) {      // u = nh*16 + itq
    const int nh = u >> 4;
    const int kq = (u & 15) * 32;
#pragma unroll
    for (int j = 0; j < 5; ++j) {
      const int bb = wave + j * 8;
      if (bb < 32) {          // QT frag block: rows = d index
        gl2lds16(QT + (size_t)(nh * 512 + bb * 16 + l15) * LQ + kq + q8,
                 buf + bb * 1024);
      } else if (bb < 36) {   // P frag block: rows = context rows
        const int mt = bb - 32;
        gl2lds16(P + (size_t)(c0 + mt * 16 + l15) * LQ + kq + q8,
                 buf + 32768 + mt * 1024);
      }
    }
  };

  auto compute = [&](const char* buf) {
    half8 af[4], bf[4];
#pragma unroll
    for (int mt = 0; mt < 4; ++mt)
      af[mt] = *(const half8*)(buf + 32768 + mt * 1024 + lane * 16);
#pragma unroll
    for (int nt = 0; nt < 4; ++nt)
      bf[nt] = *(const half8*)(buf + (wave * 4 + nt) * 1024 + lane * 16);
    __builtin_amdgcn_s_setprio(1);
#pragma unroll
    for (int mt = 0; mt < 4; ++mt)
#pragma unroll
      for (int nt = 0; nt < 4; ++nt)
        acc[mt][nt] = __builtin_amdgcn_mfma_f32_16x16x32_f16(
            af[mt], bf[nt], acc[mt][nt], 0, 0, 0);
    __builtin_amdgcn_s_setprio(0);
  };

#pragma unroll
  for (int i = 0; i < 4; ++i)
#pragma unroll
    for (int j = 0; j < 4; ++j) acc[i][j] = floatx4{0.f, 0.f, 0.f, 0.f};

  // ==== Phase 1: S = C_tile (64xK) * Q^T (Kx512), ring of 4, depth-3 =====
  stage1(0, smem);
  stage1(1, smem + BUFSZ);
  stage1(2, smem + 2 * BUFSZ);
#pragma unroll 1
  for (int t = 0; t < 32; ++t) {
    // wait for tile t (keep tiles t+1, t+2 in flight)
    if (t <= 29)      WAITV(10, 8);
    else if (t == 30) WAITV(5, 4);
    else asm volatile("s_waitcnt vmcnt(0)" ::: "memory");
    __builtin_amdgcn_s_barrier();                 // all waves: buf[t&3] staged
    __builtin_amdgcn_sched_barrier(0);
    if (t + 3 < 32) stage1(t + 3, smem + ((t + 3) & 3) * BUFSZ);
    compute(smem + (t & 3) * BUFSZ);
    asm volatile("" ::: "memory");
    __builtin_amdgcn_s_barrier();                 // buf[t&3] free to overwrite
  }

  // ================= softmax over n (=Lq) per context row ================
  // C/D layout: col = l15, row = quad*4 + reg  [m89/m91]
#pragma unroll
  for (int mt = 0; mt < 4; ++mt)
#pragma unroll
    for (int r = 0; r < 4; ++r) {
      float m = fmaxf(fmaxf(acc[mt][0][r], acc[mt][1][r]),
                      fmaxf(acc[mt][2][r], acc[mt][3][r]));
      m = fmaxf(m, __shfl_xor(m, 1, 64));
      m = fmaxf(m, __shfl_xor(m, 2, 64));
      m = fmaxf(m, __shfl_xor(m, 4, 64));
      m = fmaxf(m, __shfl_xor(m, 8, 64));
      if (l15 == 0) redf[wave * 64 + mt * 16 + quad * 4 + r] = m;
    }
  __syncthreads();
  if (tid < 64) {
    float m = redf[tid];
#pragma unroll
    for (int w = 1; w < 8; ++w) m = fmaxf(m, redf[w * 64 + tid]);
    rowstat[tid] = m;
  }
  __syncthreads();
#pragma unroll
  for (int mt = 0; mt < 4; ++mt)
#pragma unroll
    for (int r = 0; r < 4; ++r) {
      const float m = rowstat[mt * 16 + quad * 4 + r];
      float s = 0.f;
#pragma unroll
      for (int nt = 0; nt < 4; ++nt) {
        const float e = __expf(acc[mt][nt][r] - m);
        acc[mt][nt][r] = e;
        s += e;
      }
      s += __shfl_xor(s, 1, 64);
      s += __shfl_xor(s, 2, 64);
      s += __shfl_xor(s, 4, 64);
      s += __shfl_xor(s, 8, 64);
      if (l15 == 0) redf[wave * 64 + mt * 16 + quad * 4 + r] = s;
    }
  __syncthreads();
  if (tid < 64) {
    float s = 0.f;
#pragma unroll
    for (int w = 0; w < 8; ++w) s += redf[w * 64 + tid];
    rowstat[tid] = 1.0f / s;
  }
  __syncthreads();
  // write P (fp16) to workspace — L2-resident, read back by this block only
#pragma unroll
  for (int mt = 0; mt < 4; ++mt)
#pragma unroll
    for (int r = 0; r < 4; ++r) {
      const float inv = rowstat[mt * 16 + quad * 4 + r];
      const size_t rowoff =
          (size_t)(c0 + mt * 16 + quad * 4 + r) * LQ + wave * 64 + l15;
#pragma unroll
      for (int nt = 0; nt < 4; ++nt)
        P[rowoff + nt * 16] = f2h(acc[mt][nt][r] * inv);
    }
  asm volatile("s_waitcnt vmcnt(0)" ::: "memory");  // drain P stores
  __syncthreads();                                  // all waves' P visible

  // ==== Phase 2: O = P (64x512) * Q (512x1024), ring of 4, depth-3 =======
  stage2(0, smem);
  stage2(1, smem + BUFSZ);
  stage2(2, smem + 2 * BUFSZ);
#pragma unroll 1
  for (int u = 0; u < 32; ++u) {
    if ((u & 15) == 0) {
#pragma unroll
      for (int i = 0; i < 4; ++i)
#pragma unroll
        for (int j = 0; j < 4; ++j) acc[i][j] = floatx4{0.f, 0.f, 0.f, 0.f};
    }
    if (u <= 29)      WAITV(10, 8);
    else if (u == 30) WAITV(5, 4);
    else asm volatile("s_waitcnt vmcnt(0)" ::: "memory");
    __builtin_amdgcn_s_barrier();
    __builtin_amdgcn_sched_barrier(0);
    if (u + 3 < 32) stage2(u + 3, smem + ((u + 3) & 3) * BUFSZ);
    compute(smem + (u & 3) * BUFSZ);
    asm volatile("" ::: "memory");
    __builtin_amdgcn_s_barrier();
    if ((u & 15) == 15) {
      // epilogue: out[:, D + nh*512 + col] = O chunk (fp32)
      const int nh = u >> 4;
#pragma unroll
      for (int mt = 0; mt < 4; ++mt)
#pragma unroll
        for (int r = 0; r < 4; ++r) {
          const size_t rowoff = (size_t)(c0 + mt * 16 + quad * 4 + r) * DO +
                                D_ + nh * 512 + wave * 64 + l15;
#pragma unroll
          for (int nt = 0; nt < 4; ++nt)
            O[rowoff + nt * 16] = acc[mt][nt][r];
        }
    }
  }
}

extern "C" void kernel_launch(void* const* d_in, const int* in_sizes, int n_in,
                              void* d_out, int out_size, void* d_ws, size_t ws_size,
                              hipStream_t stream) {
  (void)in_sizes; (void)n_in; (void)out_size; (void)ws_size;
  const float* q = (const float*)d_in[0];
  const float* c = (const float*)d_in[1];
  float* out = (float*)d_out;
  // workspace layout (fp16 halves): Qh 16MiB | Ch 64MiB | QTh 16MiB | P 32MiB
  unsigned short* qh  = (unsigned short*)d_ws;
  unsigned short* ch  = qh  + (size_t)B_ * LQ * D_;
  unsigned short* qth = ch  + (size_t)B_ * LC * D_;
  unsigned short* p   = qth + (size_t)B_ * D_ * LQ;
  qprep_kernel<<<dim3(D_ / 32, LQ / 32, B_), dim3(32, 8), 0, stream>>>(q, qh, qth);
  cprep_kernel<<<2048, 256, 0, stream>>>(c, ch, out);
  attn_main<<<dim3(B_ * (LC / MT)), dim3(512), 0, stream>>>(qh, ch, qth, p, out);
}

// Round 4
// 516.749 us; speedup vs baseline: 1.1364x; 1.0949x over previous
//
#include <hip/hip_runtime.h>

#define GAS __attribute__((address_space(1)))
#define LAS __attribute__((address_space(3)))

typedef __attribute__((ext_vector_type(8))) _Float16 half8;
typedef __attribute__((ext_vector_type(4))) float floatx4;
typedef __attribute__((ext_vector_type(4))) unsigned short ushort4v;

static constexpr int B_  = 16;
static constexpr int LQ  = 512;
static constexpr int LC  = 2048;
static constexpr int D_  = 1024;
static constexpr int DO  = 2048;   // output feature dim (concat)
static constexpr int MT  = 128;    // context rows per block (was 64)
static constexpr int BUFSZ = 40960; // 32 KiB Q-frag blocks + 8 KiB C-frag blocks

__device__ __forceinline__ void gl2lds16(const void* g, void* l) {
  __builtin_amdgcn_global_load_lds((const GAS unsigned int*)g,
                                   (LAS unsigned int*)l, 16, 0, 0);
}

__device__ __forceinline__ unsigned short f2h(float f) {
  return __builtin_bit_cast(unsigned short, (_Float16)f);   // v_cvt_f16_f32 RNE
}

// ---- Q prep: fp32 -> fp16 qh[b][q][d] AND transposed qth[b][d][q] ----
__global__ void qprep_kernel(const float* __restrict__ q,
                             unsigned short* __restrict__ qh,
                             unsigned short* __restrict__ qt) {
  __shared__ unsigned short t[32][33];
  const int b = blockIdx.z, d0 = blockIdx.x * 32, q0 = blockIdx.y * 32;
  const float* src = q + (size_t)b * LQ * D_;
  unsigned short* dq = qh + (size_t)b * LQ * D_;
  unsigned short* dt = qt + (size_t)b * D_ * LQ;
  for (int i = threadIdx.y; i < 32; i += 8) {
    const unsigned short h = f2h(src[(size_t)(q0 + i) * D_ + d0 + threadIdx.x]);
    dq[(size_t)(q0 + i) * D_ + d0 + threadIdx.x] = h;
    t[i][threadIdx.x] = h;
  }
  __syncthreads();
  for (int i = threadIdx.y; i < 32; i += 8)
    dt[(size_t)(d0 + i) * LQ + q0 + threadIdx.x] = t[threadIdx.x][i];
}

// ---- C prep: fp32 -> fp16 ch, PLUS passthrough out[:, :D] = context ----
__global__ void cprep_kernel(const float* __restrict__ src,
                             unsigned short* __restrict__ dst,
                             float* __restrict__ out) {
  const int nrows = B_ * LC;
  for (int row = blockIdx.x; row < nrows; row += gridDim.x) {
    const float4 v = ((const float4*)(src + (size_t)row * D_))[threadIdx.x];
    ushort4v h;
    h.x = f2h(v.x); h.y = f2h(v.y); h.z = f2h(v.z); h.w = f2h(v.w);
    ((ushort4v*)(dst + (size_t)row * D_))[threadIdx.x] = h;
    ((float4*)(out + (size_t)row * DO))[threadIdx.x] = v;
  }
}

__launch_bounds__(512, 1)
__global__ void attn_main(const unsigned short* __restrict__ qg,   // Qh fp16
                          const unsigned short* __restrict__ cg,   // Ch fp16
                          const unsigned short* __restrict__ qtg,  // QTh fp16
                          unsigned short* __restrict__ pg,         // P fp16 ws
                          float* __restrict__ og) {                // out fp32
  // LDS: 3 x 40 KiB ring (depth-2 prefetch) + softmax reduction scratch
  __shared__ __align__(16) char smem[3 * BUFSZ + 4096 + 512];
  float* redf    = (float*)(smem + 3 * BUFSZ);          // [8 waves][128 rows]
  float* rowstat = (float*)(smem + 3 * BUFSZ + 4096);   // [128] rowmax / rowinv

  const int tid  = threadIdx.x;
  const int wave = tid >> 6;
  const int lane = tid & 63;
  const int l15  = lane & 15;
  const int quad = lane >> 4;
  const int q8   = quad * 8;

  const int b    = blockIdx.x & 15;   // batch b -> XCD b%8 (2 batches/XCD)
  const int tile = blockIdx.x >> 4;
  const int c0   = tile * MT;

  const unsigned short* Q  = qg  + (size_t)b * LQ * D_;
  const unsigned short* C  = cg  + (size_t)b * LC * D_;
  const unsigned short* QT = qtg + (size_t)b * D_ * LQ;
  unsigned short*       P  = pg  + (size_t)b * LC * LQ;
  float*                O  = og  + (size_t)b * LC * DO;

  floatx4 acc[8][4];   // 128 rows x 64 cols per wave

  // 40 loads/iter, exactly 5 per wave: bb = wave + j*8, j=0..4
  auto stage1 = [&](int it, char* buf) {
    const int k0 = it * 32;
#pragma unroll
    for (int j = 0; j < 5; ++j) {
      const int bb = wave + j * 8;
      if (bb < 32) {          // Q frag block (B operand): rows = q index
        gl2lds16(Q + (size_t)(bb * 16 + l15) * D_ + k0 + q8, buf + bb * 1024);
      } else {                // C frag block (A operand): mt = wave
        const int mt = bb - 32;
        gl2lds16(C + (size_t)(c0 + mt * 16 + l15) * D_ + k0 + q8,
                 buf + 32768 + mt * 1024);
      }
    }
  };

  auto stage2 = [&](int u, char* buf) {      // u = nh*16 + itq
    const int nh = u >> 4;
    const int kq = (u & 15) * 32;
#pragma unroll
    for (int j = 0; j < 5; ++j) {
      const int bb = wave + j * 8;
      if (bb < 32) {          // QT frag block: rows = d index
        gl2lds16(QT + (size_t)(nh * 512 + bb * 16 + l15) * LQ + kq + q8,
                 buf + bb * 1024);
      } else {                // P frag block: mt = wave
        const int mt = bb - 32;
        gl2lds16(P + (size_t)(c0 + mt * 16 + l15) * LQ + kq + q8,
                 buf + 32768 + mt * 1024);
      }
    }
  };

  auto compute = [&](const char* buf) {
    half8 bf[4];
#pragma unroll
    for (int nt = 0; nt < 4; ++nt)
      bf[nt] = *(const half8*)(buf + (wave * 4 + nt) * 1024 + lane * 16);
    __builtin_amdgcn_s_setprio(1);
#pragma unroll
    for (int mt = 0; mt < 8; ++mt) {
      const half8 a = *(const half8*)(buf + 32768 + mt * 1024 + lane * 16);
#pragma unroll
      for (int nt = 0; nt < 4; ++nt)
        acc[mt][nt] = __builtin_amdgcn_mfma_f32_16x16x32_f16(
            a, bf[nt], acc[mt][nt], 0, 0, 0);
    }
    __builtin_amdgcn_s_setprio(0);
  };

#pragma unroll
  for (int i = 0; i < 8; ++i)
#pragma unroll
    for (int j = 0; j < 4; ++j) acc[i][j] = floatx4{0.f, 0.f, 0.f, 0.f};

  // ==== Phase 1: S = C_tile (128xK) * Q^T (Kx512), ring of 3, depth-2 ====
  stage1(0, smem);
  stage1(1, smem + BUFSZ);
  int cur = 0;                 // buffer index of tile t
#pragma unroll 1
  for (int t = 0; t < 32; ++t) {
    if (t < 31) asm volatile("s_waitcnt vmcnt(5)" ::: "memory");
    else        asm volatile("s_waitcnt vmcnt(0)" ::: "memory");
    __builtin_amdgcn_s_barrier();                 // buf[cur] staged for all
    __builtin_amdgcn_sched_barrier(0);
    if (t + 2 < 32) {
      int s2 = cur + 2; if (s2 >= 3) s2 -= 3;
      stage1(t + 2, smem + s2 * BUFSZ);
    }
    compute(smem + cur * BUFSZ);
    asm volatile("" ::: "memory");
    __builtin_amdgcn_s_barrier();                 // buf[cur] free to overwrite
    if (++cur == 3) cur = 0;
  }

  // ================= softmax over n (=Lq) per context row ================
  // C/D layout: col = l15, row = quad*4 + reg  [m89/m91]
#pragma unroll
  for (int mt = 0; mt < 8; ++mt)
#pragma unroll
    for (int r = 0; r < 4; ++r) {
      float m = fmaxf(fmaxf(acc[mt][0][r], acc[mt][1][r]),
                      fmaxf(acc[mt][2][r], acc[mt][3][r]));
      m = fmaxf(m, __shfl_xor(m, 1, 64));
      m = fmaxf(m, __shfl_xor(m, 2, 64));
      m = fmaxf(m, __shfl_xor(m, 4, 64));
      m = fmaxf(m, __shfl_xor(m, 8, 64));
      if (l15 == 0) redf[wave * 128 + mt * 16 + quad * 4 + r] = m;
    }
  __syncthreads();
  if (tid < 128) {
    float m = redf[tid];
#pragma unroll
    for (int w = 1; w < 8; ++w) m = fmaxf(m, redf[w * 128 + tid]);
    rowstat[tid] = m;
  }
  __syncthreads();
#pragma unroll
  for (int mt = 0; mt < 8; ++mt)
#pragma unroll
    for (int r = 0; r < 4; ++r) {
      const float m = rowstat[mt * 16 + quad * 4 + r];
      float s = 0.f;
#pragma unroll
      for (int nt = 0; nt < 4; ++nt) {
        const float e = __expf(acc[mt][nt][r] - m);
        acc[mt][nt][r] = e;
        s += e;
      }
      s += __shfl_xor(s, 1, 64);
      s += __shfl_xor(s, 2, 64);
      s += __shfl_xor(s, 4, 64);
      s += __shfl_xor(s, 8, 64);
      if (l15 == 0) redf[wave * 128 + mt * 16 + quad * 4 + r] = s;
    }
  __syncthreads();
  if (tid < 128) {
    float s = 0.f;
#pragma unroll
    for (int w = 0; w < 8; ++w) s += redf[w * 128 + tid];
    rowstat[tid] = 1.0f / s;
  }
  __syncthreads();
  // write P (fp16) to workspace — read back by this block only
#pragma unroll
  for (int mt = 0; mt < 8; ++mt)
#pragma unroll
    for (int r = 0; r < 4; ++r) {
      const float inv = rowstat[mt * 16 + quad * 4 + r];
      const size_t rowoff =
          (size_t)(c0 + mt * 16 + quad * 4 + r) * LQ + wave * 64 + l15;
#pragma unroll
      for (int nt = 0; nt < 4; ++nt)
        P[rowoff + nt * 16] = f2h(acc[mt][nt][r] * inv);
    }
  asm volatile("s_waitcnt vmcnt(0)" ::: "memory");  // drain P stores
  __syncthreads();                                  // all waves' P visible

  // ==== Phase 2: O = P (128x512) * Q (512x1024), ring of 3, depth-2 ======
  stage2(0, smem);
  stage2(1, smem + BUFSZ);
  cur = 0;
#pragma unroll 1
  for (int u = 0; u < 32; ++u) {
    if ((u & 15) == 0) {
#pragma unroll
      for (int i = 0; i < 8; ++i)
#pragma unroll
        for (int j = 0; j < 4; ++j) acc[i][j] = floatx4{0.f, 0.f, 0.f, 0.f};
    }
    if (u < 31) asm volatile("s_waitcnt vmcnt(5)" ::: "memory");
    else        asm volatile("s_waitcnt vmcnt(0)" ::: "memory");
    __builtin_amdgcn_s_barrier();
    __builtin_amdgcn_sched_barrier(0);
    if (u + 2 < 32) {
      int s2 = cur + 2; if (s2 >= 3) s2 -= 3;
      stage2(u + 2, smem + s2 * BUFSZ);
    }
    compute(smem + cur * BUFSZ);
    asm volatile("" ::: "memory");
    __builtin_amdgcn_s_barrier();
    if (++cur == 3) cur = 0;
    if ((u & 15) == 15) {
      // epilogue: out[:, D + nh*512 + col] = O chunk (fp32)
      const int nh = u >> 4;
#pragma unroll
      for (int mt = 0; mt < 8; ++mt)
#pragma unroll
        for (int r = 0; r < 4; ++r) {
          const size_t rowoff = (size_t)(c0 + mt * 16 + quad * 4 + r) * DO +
                                D_ + nh * 512 + wave * 64 + l15;
#pragma unroll
          for (int nt = 0; nt < 4; ++nt)
            O[rowoff + nt * 16] = acc[mt][nt][r];
        }
    }
  }
}

extern "C" void kernel_launch(void* const* d_in, const int* in_sizes, int n_in,
                              void* d_out, int out_size, void* d_ws, size_t ws_size,
                              hipStream_t stream) {
  (void)in_sizes; (void)n_in; (void)out_size; (void)ws_size;
  const float* q = (const float*)d_in[0];
  const float* c = (const float*)d_in[1];
  float* out = (float*)d_out;
  // workspace layout (fp16 halves): Qh 16MiB | Ch 64MiB | QTh 16MiB | P 32MiB
  unsigned short* qh  = (unsigned short*)d_ws;
  unsigned short* ch  = qh  + (size_t)B_ * LQ * D_;
  unsigned short* qth = ch  + (size_t)B_ * LC * D_;
  unsigned short* p   = qth + (size_t)B_ * D_ * LQ;
  qprep_kernel<<<dim3(D_ / 32, LQ / 32, B_), dim3(32, 8), 0, stream>>>(q, qh, qth);
  cprep_kernel<<<2048, 256, 0, stream>>>(c, ch, out);
  attn_main<<<dim3(B_ * (LC / MT)), dim3(512), 0, stream>>>(qh, ch, qth, p, out);
}